// Round 19
// baseline (260.474 us; speedup 1.0000x reference)
//
#include <hip/hip_runtime.h>
#include <hip/hip_bf16.h>

typedef __hip_bfloat16 bf16;
typedef __attribute__((ext_vector_type(8)))  short bf16x8v;  // 8 bf16 (4 VGPRs) MFMA operand
typedef __attribute__((ext_vector_type(16))) float f32x16;   // 32x32 MFMA accumulator
typedef __attribute__((ext_vector_type(4)))  short short4v;  // 8B packed bf16 store

#define B_SZ   2048
#define NSTEP  128
#define DD     100
#define DX     100
#define DH     256

__device__ __constant__ const float DT_   = 0.0078125f;              // 1/128
__device__ __constant__ const float SQDT_ = 0.08838834764831845f;    // sqrt(1/128)
// sqrt(2)*sqrt(dt) = sqrt(2/128) = 1/8 exactly
__device__ __constant__ const float C1_   = 0.125f;

// ---------------------------------------------------------------------------
// Pack kernel (merged, R11-proven): 4x weight-frag packs + bias pack.
// Weight fragments for 32x32x16 MFMA: c-major, frag# = c*NTILE+t,
// elem idx = frag#*512 + lane*8 + j; n = t*32+(lane&31), k = c*16+(lane>>5)*8+j.
// OOR -> 0 (handles K=101->112 and N=100->128 padding).
// ---------------------------------------------------------------------------
__global__ __launch_bounds__(256) void pack_kernel(
    const float* __restrict__ Wi, const float* __restrict__ Wh1,
    const float* __restrict__ Wh2, const float* __restrict__ Wo,
    const float* __restrict__ bi, const float* __restrict__ bh1,
    const float* __restrict__ bh2, const float* __restrict__ bo,
    bf16* __restrict__ wfWi, bf16* __restrict__ wfWh1,
    bf16* __restrict__ wfWh2, bf16* __restrict__ wfWo,
    float* __restrict__ biases)
{
    const int bid = blockIdx.x;
    const float* W; bf16* dst; int Kact, Nact, NTILE, total, base;
    if (bid < 112)      { W = Wi;  dst = wfWi;  Kact = 101; Nact = 256; NTILE = 8; total = 28672; base = 0;   }
    else if (bid < 368) { W = Wh1; dst = wfWh1; Kact = 256; Nact = 256; NTILE = 8; total = 65536; base = 112; }
    else if (bid < 624) { W = Wh2; dst = wfWh2; Kact = 256; Nact = 256; NTILE = 8; total = 65536; base = 368; }
    else if (bid < 752) { W = Wo;  dst = wfWo;  Kact = 256; Nact = 100; NTILE = 4; total = 32768; base = 624; }
    else {
        int i = (bid - 752) * 256 + threadIdx.x;
        if (i < 256) biases[i] = bi[i];
        else if (i < 512) biases[i] = bh1[i - 256];
        else if (i < 768) biases[i] = bh2[i - 512];
        else if (i < 896) biases[i] = (i - 768 < DD) ? bo[i - 768] : 0.f;
        return;
    }
    int idx = (bid - base) * 256 + threadIdx.x;
    if (idx >= total) return;
    int j = idx & 7;
    int l = (idx >> 3) & 63;
    int frag = idx >> 9;
    int t = frag % NTILE;
    int c = frag / NTILE;
    int n = t * 32 + (l & 31);
    int k = c * 16 + (l >> 5) * 8 + j;
    float v = (k < Kact && n < Nact) ? W[(size_t)k * Nact + n] : 0.f;
    dst[idx] = __float2bfloat16(v);
}

// ---------------------------------------------------------------------------
// Kernel 1: x-prefix CHECKPOINTS only (R13-proven).
// ---------------------------------------------------------------------------
__global__ __launch_bounds__(128) void xprep_kernel(
    const float* __restrict__ Wn, const float* __restrict__ x0,
    float* __restrict__ xckpt, float* __restrict__ xout)
{
    __shared__ float w_l[DD * 129];   // padded stride 129 -> conflict-free
    const int b = blockIdx.x, tid = threadIdx.x;
    const float* wb = Wn + (size_t)b * DD * NSTEP;

    for (int idx = tid; idx < DD * NSTEP; idx += 128) {
        int d = idx >> 7, i = idx & 127;
        w_l[d * 129 + i] = wb[idx];
    }
    __syncthreads();

    if (tid < DD) {
        float x = x0[tid];
#pragma unroll 1
        for (int i = 0; i < NSTEP; ++i) {
            if ((i & 31) == 0)
                xckpt[((size_t)b * 4 + (i >> 5)) * DX + tid] = x;
            x += C1_ * w_l[tid * 129 + i];
        }
        xout[(size_t)b * DX + tid] = x;   // exact f32 final x
    }
}

// ---------------------------------------------------------------------------
// One 32x32x16-MFMA layer, IN PLACE, 64-row tile, 4-way n-split.
// Pipeline: b-frags (LDS) 1-deep; a-frags (L2) 2-deep (R18-proven).
// Swizzle: byte ^= (m&15)<<4.
// ---------------------------------------------------------------------------
template<int KC, int NTT, int NT, bool RELU>
__device__ __forceinline__ void layer32(
    char* __restrict__ buf,
    const bf16* __restrict__ wfrag, const float* __restrict__ bias,
    int lane, int t0)
{
    const int mrow = lane & 31;   // m within tile (B col)
    const int kg   = lane >> 5;   // k-group (0/1)
    const int ma = mrow, mb = 32 + mrow;
    const int sa = (ma & 15) << 4, sb = (mb & 15) << 4;

    f32x16 acc[NT][2];
#pragma unroll
    for (int t = 0; t < NT; ++t)
#pragma unroll
        for (int mt = 0; mt < 2; ++mt)
#pragma unroll
            for (int e = 0; e < 16; ++e) acc[t][mt][e] = 0.f;

    const char* wptr = (const char*)wfrag + (size_t)t0 * 1024 + (size_t)lane * 16;

    // pipeline preload: b for c=0 (1-deep); a for c=0 and c=1 (2-deep)
    bf16x8v bc0 = *(const bf16x8v*)(buf + ma * 512 + ((kg * 16) ^ sa));
    bf16x8v bc1 = *(const bf16x8v*)(buf + mb * 512 + ((kg * 16) ^ sb));
    bf16x8v a0[NT], a1[NT];
#pragma unroll
    for (int t = 0; t < NT; ++t) {
        a0[t] = *(const bf16x8v*)(wptr + (size_t)t * 1024);
        a1[t] = *(const bf16x8v*)(wptr + (size_t)(NTT + t) * 1024);
    }

#pragma unroll
    for (int c = 0; c < KC; ++c) {
        const int cn1 = (c + 1 < KC) ? c + 1 : c;     // b lookahead (dummy on last)
        const int cn2 = (c + 2 < KC) ? c + 2 : KC - 1; // a lookahead (clamped)
        const int ncol = cn1 * 32 + kg * 16;
        bf16x8v bn0 = *(const bf16x8v*)(buf + ma * 512 + (ncol ^ sa));
        bf16x8v bn1 = *(const bf16x8v*)(buf + mb * 512 + (ncol ^ sb));
        bf16x8v a2[NT];
#pragma unroll
        for (int t = 0; t < NT; ++t)
            a2[t] = *(const bf16x8v*)(wptr + (size_t)(cn2 * NTT + t) * 1024);

        __builtin_amdgcn_s_setprio(1);
#pragma unroll
        for (int t = 0; t < NT; ++t) {
            acc[t][0] = __builtin_amdgcn_mfma_f32_32x32x16_bf16(a0[t], bc0, acc[t][0], 0, 0, 0);
            acc[t][1] = __builtin_amdgcn_mfma_f32_32x32x16_bf16(a0[t], bc1, acc[t][1], 0, 0, 0);
        }
        __builtin_amdgcn_s_setprio(0);

        bc0 = bn0; bc1 = bn1;
#pragma unroll
        for (int t = 0; t < NT; ++t) { a0[t] = a1[t]; a1[t] = a2[t]; }
    }

    __syncthreads();   // all reads of buf complete block-wide; safe to overwrite

    // C/D layout 32x32: col(m) = lane&31, row(n) = (r&3) + 8*(r>>2) + 4*kg
#pragma unroll
    for (int t = 0; t < NT; ++t) {
#pragma unroll
        for (int g = 0; g < 4; ++g) {
            const int nb = (t0 + t) * 32 + g * 8 + kg * 4;  // 4 consecutive features
            const float4 bv = *(const float4*)(bias + nb);
#pragma unroll
            for (int mt = 0; mt < 2; ++mt) {
                const int m = mt * 32 + mrow;
                float v0 = acc[t][mt][g * 4 + 0] + bv.x;
                float v1 = acc[t][mt][g * 4 + 1] + bv.y;
                float v2 = acc[t][mt][g * 4 + 2] + bv.z;
                float v3 = acc[t][mt][g * 4 + 3] + bv.w;
                if (RELU) {
                    v0 = fmaxf(v0, 0.f); v1 = fmaxf(v1, 0.f);
                    v2 = fmaxf(v2, 0.f); v3 = fmaxf(v3, 0.f);
                }
                bf16 h0 = __float2bfloat16(v0), h1 = __float2bfloat16(v1);
                bf16 h2 = __float2bfloat16(v2), h3 = __float2bfloat16(v3);
                short4v pv;
                pv[0] = *(short*)&h0; pv[1] = *(short*)&h1;
                pv[2] = *(short*)&h2; pv[3] = *(short*)&h3;
                *(short4v*)(buf + m * 512 + ((nb * 2) ^ ((m & 15) << 4))) = pv;
            }
        }
    }
}

// ---------------------------------------------------------------------------
// Layer 4 + REGISTER-SPACE reduction (R17-proven) + 2-deep a-pipeline (R18).
// Padding features (wave 3, d>=100): weights+bias exactly 0 -> z = 0;
// noise index clamped so 0 * garbage can't make NaN.
// ---------------------------------------------------------------------------
__device__ __forceinline__ void layer4_reduce(
    const char* __restrict__ buf,
    const bf16* __restrict__ wfrag, const float* __restrict__ bias,
    const float* __restrict__ noise, const float* __restrict__ s_l32,
    float* __restrict__ Wz2, float* __restrict__ Wzw,
    int lane, int w)
{
    const int mrow = lane & 31;   // m within tile (B col)
    const int kg   = lane >> 5;   // k-group (0/1)
    const int ma = mrow, mb = 32 + mrow;
    const int sa = (ma & 15) << 4, sb = (mb & 15) << 4;
    constexpr int KC = 16, NTT = 4;

    f32x16 acc[2];
#pragma unroll
    for (int mt = 0; mt < 2; ++mt)
#pragma unroll
        for (int e = 0; e < 16; ++e) acc[mt][e] = 0.f;

    const char* wptr = (const char*)wfrag + (size_t)w * 1024 + (size_t)lane * 16;

    // pipeline preload: b c=0; a c=0,1 (2-deep)
    bf16x8v bc0 = *(const bf16x8v*)(buf + ma * 512 + ((kg * 16) ^ sa));
    bf16x8v bc1 = *(const bf16x8v*)(buf + mb * 512 + ((kg * 16) ^ sb));
    bf16x8v a0 = *(const bf16x8v*)(wptr);
    bf16x8v a1 = *(const bf16x8v*)(wptr + (size_t)NTT * 1024);

#pragma unroll
    for (int c = 0; c < KC; ++c) {
        const int cn1 = (c + 1 < KC) ? c + 1 : c;
        const int cn2 = (c + 2 < KC) ? c + 2 : KC - 1;
        const int ncol = cn1 * 32 + kg * 16;
        bf16x8v bn0 = *(const bf16x8v*)(buf + ma * 512 + (ncol ^ sa));
        bf16x8v bn1 = *(const bf16x8v*)(buf + mb * 512 + (ncol ^ sb));
        bf16x8v a2 = *(const bf16x8v*)(wptr + (size_t)(cn2 * NTT) * 1024);

        __builtin_amdgcn_s_setprio(1);
        acc[0] = __builtin_amdgcn_mfma_f32_32x32x16_bf16(a0, bc0, acc[0], 0, 0, 0);
        acc[1] = __builtin_amdgcn_mfma_f32_32x32x16_bf16(a0, bc1, acc[1], 0, 0, 0);
        __builtin_amdgcn_s_setprio(0);

        bc0 = bn0; bc1 = bn1; a0 = a1; a1 = a2;
    }

    // In-register reduction. Row r = mt*32 + mrow; jj = r>>1 = mt*16 + (mrow>>1);
    // h = r&1 = mrow&1. wt[d] = SQDT*noise[d][jj] + (h ? +sdt : -sdt).
    const int h   = mrow & 1;
    const int jr  = mrow >> 1;
    const int jj0 = jr, jj1 = 16 + jr;
    const float sdt0 = s_l32[jj0] * SQDT_;
    const float sdt1 = s_l32[jj1] * SQDT_;
    float sz2_0 = 0.f, szw_0 = 0.f, sz2_1 = 0.f, szw_1 = 0.f;
#pragma unroll
    for (int g = 0; g < 4; ++g) {
        const int nb = w * 32 + g * 8 + kg * 4;
        const float4 bv = *(const float4*)(bias + nb);
#pragma unroll
        for (int i = 0; i < 4; ++i) {
            const int d = nb + i;
            const int dcl = (d < DD) ? d : 0;          // clamp pad (z==0 there)
            const float be = (i == 0) ? bv.x : (i == 1) ? bv.y : (i == 2) ? bv.z : bv.w;
            const float z0 = acc[0][g * 4 + i] + be;   // row mrow
            const float z1 = acc[1][g * 4 + i] + be;   // row 32+mrow
            const float wv0 = SQDT_ * noise[dcl * 33 + jj0];
            const float wv1 = SQDT_ * noise[dcl * 33 + jj1];
            const float wt0 = h ? (wv0 + sdt0) : (wv0 - sdt0);
            const float wt1 = h ? (wv1 + sdt1) : (wv1 - sdt1);
            sz2_0 += z0 * z0;  szw_0 += z0 * wt0;
            sz2_1 += z1 * z1;  szw_1 += z1 * wt1;
        }
    }
    // combine kg partner (lane^32 holds the other 4-feature half of each group)
    sz2_0 += __shfl_xor(sz2_0, 32);  szw_0 += __shfl_xor(szw_0, 32);
    sz2_1 += __shfl_xor(sz2_1, 32);  szw_1 += __shfl_xor(szw_1, 32);
    if (lane < 32) {
        Wz2[w * 64 + mrow]      = sz2_0;
        Wzw[w * 64 + mrow]      = szw_0;
        Wz2[w * 64 + 32 + mrow] = sz2_1;
        Wzw[w * 64 + 32 + mrow] = szw_1;
    }
}

// ---------------------------------------------------------------------------
// Kernel 2: ONE CHUNK per block (R13/R17/R18-proven structure) + faster
// B-phase build: 200-thread split (h=0 and h=1 threads run the IDENTICAL
// prefix-add chain -> bitwise-identical x; each writes only its row parity,
// halving per-thread stores) + unroll 4 (4 independent noise reads issue
// together, cutting the read-latency chain ~4x; 4-not-32 avoids R11's
// full-unroll register bomb).
// ---------------------------------------------------------------------------
__global__ __launch_bounds__(256, 3) void mlp_kernel(
    const float* __restrict__ Wn, const int* __restrict__ signs,
    const float* __restrict__ xckpt,
    const bf16* __restrict__ wfWi, const bf16* __restrict__ wfWh1,
    const bf16* __restrict__ wfWh2, const bf16* __restrict__ wfWo,
    const float* __restrict__ biases, float* __restrict__ incr)
{
    __shared__ char  buf[64 * 512];        // 32KB working tile
    __shared__ float noise[DD * 33];       // 13.2KB, padded stride 33
    __shared__ float s_l32[32];
    __shared__ float Wz2[256], Wzw[256];   // per-wave row partials
    const int tid = threadIdx.x;
    const int lane = tid & 63, w = tid >> 6;
    const int b = blockIdx.x >> 2, ch = blockIdx.x & 3;
    const int i0 = ch * 32;
    const size_t row0 = (size_t)blockIdx.x * 64;
    const float* wnb = Wn + (size_t)b * DD * NSTEP;

    // A: noise chunk -> LDS (coalesced: 32 consecutive floats per d) + signs
    for (int idx = tid; idx < DD * 32; idx += 256) {
        int d = idx >> 5, j = idx & 31;
        noise[d * 33 + j] = wnb[d * NSTEP + i0 + j];
    }
    if (tid < 32) s_l32[tid] = 2.f * (float)signs[i0 + tid] - 1.f;
    __syncthreads();

    // B: build 64 U rows in buf. Row r = 2j+h: cols 0..99 = x-part,
    // col 100 = t, 101..111 = 0 (layer 1 reads bytes 0..223).
    // 200-thread split: tid<100 -> (d, h=0); 100<=tid<200 -> (d-100, h=1).
    // Both run the same f32 add chain (same loads, same order) -> bitwise
    // identical to the reference prefix.
    if (tid < 200) {
        const int d = (tid < 100) ? tid : tid - 100;
        const int hh = (tid < 100) ? 0 : 1;
        float x = xckpt[((size_t)b * 4 + ch) * DX + d];
#pragma unroll 4
        for (int j = 0; j < 32; ++j) {
            float wn = noise[d * 33 + j];
            int r = j * 2 + hh;
            float v = hh ? (x + C1_ * (wn - s_l32[j])) : x;
            bf16 hv = __float2bfloat16(v);
            *(short*)(buf + r * 512 + ((d * 2) ^ ((r & 15) << 4))) = *(short*)&hv;
            x += C1_ * wn;
        }
    } else {
        // pad/t-col writers: 56 threads cover 64 rows (8 do two rows)
#pragma unroll 2
        for (int r = tid - 200; r < 64; r += 56) {
            const int i = i0 + (r >> 1), hh = r & 1;
            bf16 tv = __float2bfloat16(DT_ * (float)(i + hh));
            char* rb = buf + r * 512;
            const int sw = (r & 15) << 4;
            *(short*)(rb + (200 ^ sw)) = *(short*)&tv;
            *(short*)(rb + (202 ^ sw)) = 0;
            *(short*)(rb + (204 ^ sw)) = 0;
            *(short*)(rb + (206 ^ sw)) = 0;
            *(uint4*)(rb + (208 ^ sw)) = (uint4){0, 0, 0, 0};
        }
    }
    __syncthreads();

    // C: 3x layer32 + fused layer-4/reduction
    layer32<7,  8, 2, true >(buf, wfWi,  biases,        lane, w * 2);
    __syncthreads();
    layer32<16, 8, 2, true >(buf, wfWh1, biases + 256,  lane, w * 2);
    __syncthreads();
    layer32<16, 8, 2, true >(buf, wfWh2, biases + 512,  lane, w * 2);
    __syncthreads();
    layer4_reduce(buf, wfWo, biases + 768, noise, s_l32, Wz2, Wzw, lane, w);
    __syncthreads();

    // Final combine: incr = -||z||^2*dt + 0.5*(z.(w-sdt) + z_new.(w+sdt));
    // z from h=0 row (rr), z_new from h=1 row (rr+1); sum 4 wave partials.
    if (tid < 32) {
        const int rr = tid * 2;
        float sz2 = 0.f, szw0 = 0.f, szw1 = 0.f;
#pragma unroll
        for (int ww = 0; ww < 4; ++ww) {
            sz2  += Wz2[ww * 64 + rr];
            szw0 += Wzw[ww * 64 + rr];
            szw1 += Wzw[ww * 64 + rr + 1];
        }
        incr[row0 / 2 + tid] = -sz2 * DT_ + 0.5f * (szw0 + szw1);
    }
}

// ---------------------------------------------------------------------------
// Kernel 3: y[b] = y0 + sum_i incr[b*128+i]
// ---------------------------------------------------------------------------
__global__ __launch_bounds__(128) void y_kernel(
    const float* __restrict__ incr, const float* __restrict__ y0,
    float* __restrict__ yout)
{
    const int b = blockIdx.x, tid = threadIdx.x;
    float v = incr[(size_t)b * NSTEP + tid];
#pragma unroll
    for (int off = 1; off < 64; off <<= 1) v += __shfl_xor(v, off);
    __shared__ float partial[2];
    if ((tid & 63) == 0) partial[tid >> 6] = v;
    __syncthreads();
    if (tid == 0) yout[b] = y0[0] + partial[0] + partial[1];
}

// ---------------------------------------------------------------------------
extern "C" void kernel_launch(void* const* d_in, const int* in_sizes, int n_in,
                              void* d_out, int out_size, void* d_ws, size_t ws_size,
                              hipStream_t stream) {
    (void)in_sizes; (void)n_in; (void)out_size; (void)ws_size;
    const float* Wn    = (const float*)d_in[0];
    const int*   signs = (const int*)d_in[1];
    const float* x0    = (const float*)d_in[2];
    const float* y0    = (const float*)d_in[3];
    const float* Wi    = (const float*)d_in[4];
    const float* bi    = (const float*)d_in[5];
    const float* Wh1   = (const float*)d_in[6];
    const float* bh1   = (const float*)d_in[7];
    const float* Wh2   = (const float*)d_in[8];
    const float* bh2   = (const float*)d_in[9];
    const float* Wo    = (const float*)d_in[10];
    const float* bo    = (const float*)d_in[11];

    float* out  = (float*)d_out;
    float* xout = out;                       // [2048,100]
    float* yout = out + (size_t)B_SZ * DX;   // [2048,1]

    char* ws = (char*)d_ws;
    size_t off = 0;
    bf16*  wfWi   = (bf16*)(ws + off); off += 28672 * sizeof(bf16);   // KC=7,  8 tiles
    bf16*  wfWh1  = (bf16*)(ws + off); off += 65536 * sizeof(bf16);   // KC=16, 8 tiles
    bf16*  wfWh2  = (bf16*)(ws + off); off += 65536 * sizeof(bf16);
    bf16*  wfWo   = (bf16*)(ws + off); off += 32768 * sizeof(bf16);   // KC=16, 4 tiles
    float* biases = (float*)(ws + off); off += 896 * sizeof(float);
    float* xckpt  = (float*)(ws + off); off += (size_t)B_SZ * 4 * DX * sizeof(float);  // 3.3MB
    float* incr   = (float*)(ws + off); off += (size_t)B_SZ * NSTEP * sizeof(float);   // 1MB

    pack_kernel<<<756, 256, 0, stream>>>(Wi, Wh1, Wh2, Wo, bi, bh1, bh2, bo,
                                         wfWi, wfWh1, wfWh2, wfWo, biases);
    xprep_kernel<<<B_SZ, 128, 0, stream>>>(Wn, x0, xckpt, xout);
    mlp_kernel<<<B_SZ * 4, 256, 0, stream>>>(Wn, signs, xckpt,
                                             wfWi, wfWh1, wfWh2, wfWo, biases, incr);
    y_kernel<<<B_SZ, 128, 0, stream>>>(incr, y0, yout);
}

// Round 20
// 257.388 us; speedup vs baseline: 1.0120x; 1.0120x over previous
//
#include <hip/hip_runtime.h>
#include <hip/hip_bf16.h>

typedef __hip_bfloat16 bf16;
typedef __attribute__((ext_vector_type(8)))  short bf16x8v;  // 8 bf16 (4 VGPRs) MFMA operand
typedef __attribute__((ext_vector_type(16))) float f32x16;   // 32x32 MFMA accumulator
typedef __attribute__((ext_vector_type(4)))  short short4v;  // 8B packed bf16 store

#define B_SZ   2048
#define NSTEP  128
#define DD     100
#define DX     100
#define DH     256

__device__ __constant__ const float DT_   = 0.0078125f;              // 1/128
__device__ __constant__ const float SQDT_ = 0.08838834764831845f;    // sqrt(1/128)
// sqrt(2)*sqrt(dt) = sqrt(2/128) = 1/8 exactly
__device__ __constant__ const float C1_   = 0.125f;

// ---------------------------------------------------------------------------
// Kernel 1 (merged prep): blocks [0,756) do weight-frag + bias packing
// (R11-proven math); blocks [756, 756+2048) do per-batch x-prefix
// checkpoints (R13-proven) + yout init (= y0, the base for mlp's atomics).
// Weight fragments for 32x32x16 MFMA: c-major, frag# = c*NTILE+t,
// elem idx = frag#*512 + lane*8 + j; n = t*32+(lane&31), k = c*16+(lane>>5)*8+j.
// OOR -> 0 (handles K=101->112 and N=100->128 padding).
// ---------------------------------------------------------------------------
__global__ __launch_bounds__(256) void prep_kernel(
    const float* __restrict__ Wn, const float* __restrict__ x0,
    const float* __restrict__ y0,
    const float* __restrict__ Wi, const float* __restrict__ Wh1,
    const float* __restrict__ Wh2, const float* __restrict__ Wo,
    const float* __restrict__ bi, const float* __restrict__ bh1,
    const float* __restrict__ bh2, const float* __restrict__ bo,
    bf16* __restrict__ wfWi, bf16* __restrict__ wfWh1,
    bf16* __restrict__ wfWh2, bf16* __restrict__ wfWo,
    float* __restrict__ biases,
    float* __restrict__ xckpt, float* __restrict__ xout,
    float* __restrict__ yout)
{
    const int bid = blockIdx.x;
    const int tid = threadIdx.x;

    if (bid >= 756) {
        // ---- xprep section: one block per batch ----
        __shared__ float w_l[DD * 129];   // padded stride 129 -> conflict-free
        const int b = bid - 756;
        const float* wb = Wn + (size_t)b * DD * NSTEP;

        for (int idx = tid; idx < DD * NSTEP; idx += 256) {
            int d = idx >> 7, i = idx & 127;
            w_l[d * 129 + i] = wb[idx];
        }
        __syncthreads();

        if (tid < DD) {
            float x = x0[tid];
#pragma unroll 1
            for (int i = 0; i < NSTEP; ++i) {
                if ((i & 31) == 0)
                    xckpt[((size_t)b * 4 + (i >> 5)) * DX + tid] = x;
                x += C1_ * w_l[tid * 129 + i];
            }
            xout[(size_t)b * DX + tid] = x;   // exact f32 final x
        } else if (tid == 200) {
            yout[b] = y0[0];                  // base for mlp's atomic adds
        }
        return;
    }

    // ---- pack section ----
    const float* W; bf16* dst; int Kact, Nact, NTILE, total, base;
    if (bid < 112)      { W = Wi;  dst = wfWi;  Kact = 101; Nact = 256; NTILE = 8; total = 28672; base = 0;   }
    else if (bid < 368) { W = Wh1; dst = wfWh1; Kact = 256; Nact = 256; NTILE = 8; total = 65536; base = 112; }
    else if (bid < 624) { W = Wh2; dst = wfWh2; Kact = 256; Nact = 256; NTILE = 8; total = 65536; base = 368; }
    else if (bid < 752) { W = Wo;  dst = wfWo;  Kact = 256; Nact = 100; NTILE = 4; total = 32768; base = 624; }
    else {
        int i = (bid - 752) * 256 + tid;
        if (i < 256) biases[i] = bi[i];
        else if (i < 512) biases[i] = bh1[i - 256];
        else if (i < 768) biases[i] = bh2[i - 512];
        else if (i < 896) biases[i] = (i - 768 < DD) ? bo[i - 768] : 0.f;
        return;
    }
    int idx = (bid - base) * 256 + tid;
    if (idx >= total) return;
    int j = idx & 7;
    int l = (idx >> 3) & 63;
    int frag = idx >> 9;
    int t = frag % NTILE;
    int c = frag / NTILE;
    int n = t * 32 + (l & 31);
    int k = c * 16 + (l >> 5) * 8 + j;
    float v = (k < Kact && n < Nact) ? W[(size_t)k * Nact + n] : 0.f;
    dst[idx] = __float2bfloat16(v);
}

// ---------------------------------------------------------------------------
// One 32x32x16-MFMA layer, IN PLACE, 64-row tile, 4-way n-split.
// Pipeline: b-frags (LDS) 1-deep; a-frags (L2) 2-deep (R18-proven).
// Swizzle: byte ^= (m&15)<<4.
// ---------------------------------------------------------------------------
template<int KC, int NTT, int NT, bool RELU>
__device__ __forceinline__ void layer32(
    char* __restrict__ buf,
    const bf16* __restrict__ wfrag, const float* __restrict__ bias,
    int lane, int t0)
{
    const int mrow = lane & 31;   // m within tile (B col)
    const int kg   = lane >> 5;   // k-group (0/1)
    const int ma = mrow, mb = 32 + mrow;
    const int sa = (ma & 15) << 4, sb = (mb & 15) << 4;

    f32x16 acc[NT][2];
#pragma unroll
    for (int t = 0; t < NT; ++t)
#pragma unroll
        for (int mt = 0; mt < 2; ++mt)
#pragma unroll
            for (int e = 0; e < 16; ++e) acc[t][mt][e] = 0.f;

    const char* wptr = (const char*)wfrag + (size_t)t0 * 1024 + (size_t)lane * 16;

    // pipeline preload: b for c=0 (1-deep); a for c=0 and c=1 (2-deep)
    bf16x8v bc0 = *(const bf16x8v*)(buf + ma * 512 + ((kg * 16) ^ sa));
    bf16x8v bc1 = *(const bf16x8v*)(buf + mb * 512 + ((kg * 16) ^ sb));
    bf16x8v a0[NT], a1[NT];
#pragma unroll
    for (int t = 0; t < NT; ++t) {
        a0[t] = *(const bf16x8v*)(wptr + (size_t)t * 1024);
        a1[t] = *(const bf16x8v*)(wptr + (size_t)(NTT + t) * 1024);
    }

#pragma unroll
    for (int c = 0; c < KC; ++c) {
        const int cn1 = (c + 1 < KC) ? c + 1 : c;      // b lookahead (dummy on last)
        const int cn2 = (c + 2 < KC) ? c + 2 : KC - 1; // a lookahead (clamped)
        const int ncol = cn1 * 32 + kg * 16;
        bf16x8v bn0 = *(const bf16x8v*)(buf + ma * 512 + (ncol ^ sa));
        bf16x8v bn1 = *(const bf16x8v*)(buf + mb * 512 + (ncol ^ sb));
        bf16x8v a2[NT];
#pragma unroll
        for (int t = 0; t < NT; ++t)
            a2[t] = *(const bf16x8v*)(wptr + (size_t)(cn2 * NTT + t) * 1024);

        __builtin_amdgcn_s_setprio(1);
#pragma unroll
        for (int t = 0; t < NT; ++t) {
            acc[t][0] = __builtin_amdgcn_mfma_f32_32x32x16_bf16(a0[t], bc0, acc[t][0], 0, 0, 0);
            acc[t][1] = __builtin_amdgcn_mfma_f32_32x32x16_bf16(a0[t], bc1, acc[t][1], 0, 0, 0);
        }
        __builtin_amdgcn_s_setprio(0);

        bc0 = bn0; bc1 = bn1;
#pragma unroll
        for (int t = 0; t < NT; ++t) { a0[t] = a1[t]; a1[t] = a2[t]; }
    }

    __syncthreads();   // all reads of buf complete block-wide; safe to overwrite

    // C/D layout 32x32: col(m) = lane&31, row(n) = (r&3) + 8*(r>>2) + 4*kg
#pragma unroll
    for (int t = 0; t < NT; ++t) {
#pragma unroll
        for (int g = 0; g < 4; ++g) {
            const int nb = (t0 + t) * 32 + g * 8 + kg * 4;  // 4 consecutive features
            const float4 bv = *(const float4*)(bias + nb);
#pragma unroll
            for (int mt = 0; mt < 2; ++mt) {
                const int m = mt * 32 + mrow;
                float v0 = acc[t][mt][g * 4 + 0] + bv.x;
                float v1 = acc[t][mt][g * 4 + 1] + bv.y;
                float v2 = acc[t][mt][g * 4 + 2] + bv.z;
                float v3 = acc[t][mt][g * 4 + 3] + bv.w;
                if (RELU) {
                    v0 = fmaxf(v0, 0.f); v1 = fmaxf(v1, 0.f);
                    v2 = fmaxf(v2, 0.f); v3 = fmaxf(v3, 0.f);
                }
                bf16 h0 = __float2bfloat16(v0), h1 = __float2bfloat16(v1);
                bf16 h2 = __float2bfloat16(v2), h3 = __float2bfloat16(v3);
                short4v pv;
                pv[0] = *(short*)&h0; pv[1] = *(short*)&h1;
                pv[2] = *(short*)&h2; pv[3] = *(short*)&h3;
                *(short4v*)(buf + m * 512 + ((nb * 2) ^ ((m & 15) << 4))) = pv;
            }
        }
    }
}

// ---------------------------------------------------------------------------
// Layer 4 + REGISTER-SPACE reduction (R17-proven) + 2-deep a-pipeline (R18).
// Padding features (wave 3, d>=100): weights+bias exactly 0 -> z = 0;
// noise index clamped so 0 * garbage can't make NaN.
// ---------------------------------------------------------------------------
__device__ __forceinline__ void layer4_reduce(
    const char* __restrict__ buf,
    const bf16* __restrict__ wfrag, const float* __restrict__ bias,
    const float* __restrict__ noise, const float* __restrict__ s_l32,
    float* __restrict__ Wz2, float* __restrict__ Wzw,
    int lane, int w)
{
    const int mrow = lane & 31;   // m within tile (B col)
    const int kg   = lane >> 5;   // k-group (0/1)
    const int ma = mrow, mb = 32 + mrow;
    const int sa = (ma & 15) << 4, sb = (mb & 15) << 4;
    constexpr int KC = 16, NTT = 4;

    f32x16 acc[2];
#pragma unroll
    for (int mt = 0; mt < 2; ++mt)
#pragma unroll
        for (int e = 0; e < 16; ++e) acc[mt][e] = 0.f;

    const char* wptr = (const char*)wfrag + (size_t)w * 1024 + (size_t)lane * 16;

    // pipeline preload: b c=0; a c=0,1 (2-deep)
    bf16x8v bc0 = *(const bf16x8v*)(buf + ma * 512 + ((kg * 16) ^ sa));
    bf16x8v bc1 = *(const bf16x8v*)(buf + mb * 512 + ((kg * 16) ^ sb));
    bf16x8v a0 = *(const bf16x8v*)(wptr);
    bf16x8v a1 = *(const bf16x8v*)(wptr + (size_t)NTT * 1024);

#pragma unroll
    for (int c = 0; c < KC; ++c) {
        const int cn1 = (c + 1 < KC) ? c + 1 : c;
        const int cn2 = (c + 2 < KC) ? c + 2 : KC - 1;
        const int ncol = cn1 * 32 + kg * 16;
        bf16x8v bn0 = *(const bf16x8v*)(buf + ma * 512 + (ncol ^ sa));
        bf16x8v bn1 = *(const bf16x8v*)(buf + mb * 512 + (ncol ^ sb));
        bf16x8v a2 = *(const bf16x8v*)(wptr + (size_t)(cn2 * NTT) * 1024);

        __builtin_amdgcn_s_setprio(1);
        acc[0] = __builtin_amdgcn_mfma_f32_32x32x16_bf16(a0, bc0, acc[0], 0, 0, 0);
        acc[1] = __builtin_amdgcn_mfma_f32_32x32x16_bf16(a0, bc1, acc[1], 0, 0, 0);
        __builtin_amdgcn_s_setprio(0);

        bc0 = bn0; bc1 = bn1; a0 = a1; a1 = a2;
    }

    // In-register reduction. Row r = mt*32 + mrow; jj = r>>1 = mt*16 + (mrow>>1);
    // h = r&1 = mrow&1. wt[d] = SQDT*noise[d][jj] + (h ? +sdt : -sdt).
    const int h   = mrow & 1;
    const int jr  = mrow >> 1;
    const int jj0 = jr, jj1 = 16 + jr;
    const float sdt0 = s_l32[jj0] * SQDT_;
    const float sdt1 = s_l32[jj1] * SQDT_;
    float sz2_0 = 0.f, szw_0 = 0.f, sz2_1 = 0.f, szw_1 = 0.f;
#pragma unroll
    for (int g = 0; g < 4; ++g) {
        const int nb = w * 32 + g * 8 + kg * 4;
        const float4 bv = *(const float4*)(bias + nb);
#pragma unroll
        for (int i = 0; i < 4; ++i) {
            const int d = nb + i;
            const int dcl = (d < DD) ? d : 0;          // clamp pad (z==0 there)
            const float be = (i == 0) ? bv.x : (i == 1) ? bv.y : (i == 2) ? bv.z : bv.w;
            const float z0 = acc[0][g * 4 + i] + be;   // row mrow
            const float z1 = acc[1][g * 4 + i] + be;   // row 32+mrow
            const float wv0 = SQDT_ * noise[dcl * 33 + jj0];
            const float wv1 = SQDT_ * noise[dcl * 33 + jj1];
            const float wt0 = h ? (wv0 + sdt0) : (wv0 - sdt0);
            const float wt1 = h ? (wv1 + sdt1) : (wv1 - sdt1);
            sz2_0 += z0 * z0;  szw_0 += z0 * wt0;
            sz2_1 += z1 * z1;  szw_1 += z1 * wt1;
        }
    }
    // combine kg partner (lane^32 holds the other 4-feature half of each group)
    sz2_0 += __shfl_xor(sz2_0, 32);  szw_0 += __shfl_xor(szw_0, 32);
    sz2_1 += __shfl_xor(sz2_1, 32);  szw_1 += __shfl_xor(szw_1, 32);
    if (lane < 32) {
        Wz2[w * 64 + mrow]      = sz2_0;
        Wzw[w * 64 + mrow]      = szw_0;
        Wz2[w * 64 + 32 + mrow] = sz2_1;
        Wzw[w * 64 + 32 + mrow] = szw_1;
    }
}

// ---------------------------------------------------------------------------
// Kernel 2: ONE CHUNK per block (R13/R17/R18-proven structure; R19 B-phase).
// Final combine now ends with ONE atomicAdd per block into yout[b]
// (replaces the y_kernel launch + incr buffer; yout pre-initialized to y0
// by prep_kernel; atomic order changes y's f32 rounding only).
// ---------------------------------------------------------------------------
__global__ __launch_bounds__(256, 3) void mlp_kernel(
    const float* __restrict__ Wn, const int* __restrict__ signs,
    const float* __restrict__ xckpt,
    const bf16* __restrict__ wfWi, const bf16* __restrict__ wfWh1,
    const bf16* __restrict__ wfWh2, const bf16* __restrict__ wfWo,
    const float* __restrict__ biases, float* __restrict__ yout)
{
    __shared__ char  buf[64 * 512];        // 32KB working tile
    __shared__ float noise[DD * 33];       // 13.2KB, padded stride 33
    __shared__ float s_l32[32];
    __shared__ float Wz2[256], Wzw[256];   // per-wave row partials
    const int tid = threadIdx.x;
    const int lane = tid & 63, w = tid >> 6;
    const int b = blockIdx.x >> 2, ch = blockIdx.x & 3;
    const int i0 = ch * 32;
    const float* wnb = Wn + (size_t)b * DD * NSTEP;

    // A: noise chunk -> LDS (coalesced: 32 consecutive floats per d) + signs
    for (int idx = tid; idx < DD * 32; idx += 256) {
        int d = idx >> 5, j = idx & 31;
        noise[d * 33 + j] = wnb[d * NSTEP + i0 + j];
    }
    if (tid < 32) s_l32[tid] = 2.f * (float)signs[i0 + tid] - 1.f;
    __syncthreads();

    // B: build 64 U rows in buf. Row r = 2j+h: cols 0..99 = x-part,
    // col 100 = t, 101..111 = 0. 200-thread split (R19): both parities run
    // the same f32 add chain -> bitwise-identical prefix.
    if (tid < 200) {
        const int d = (tid < 100) ? tid : tid - 100;
        const int hh = (tid < 100) ? 0 : 1;
        float x = xckpt[((size_t)b * 4 + ch) * DX + d];
#pragma unroll 4
        for (int j = 0; j < 32; ++j) {
            float wn = noise[d * 33 + j];
            int r = j * 2 + hh;
            float v = hh ? (x + C1_ * (wn - s_l32[j])) : x;
            bf16 hv = __float2bfloat16(v);
            *(short*)(buf + r * 512 + ((d * 2) ^ ((r & 15) << 4))) = *(short*)&hv;
            x += C1_ * wn;
        }
    } else {
        // pad/t-col writers: 56 threads cover 64 rows (8 do two rows)
#pragma unroll 2
        for (int r = tid - 200; r < 64; r += 56) {
            const int i = i0 + (r >> 1), hh = r & 1;
            bf16 tv = __float2bfloat16(DT_ * (float)(i + hh));
            char* rb = buf + r * 512;
            const int sw = (r & 15) << 4;
            *(short*)(rb + (200 ^ sw)) = *(short*)&tv;
            *(short*)(rb + (202 ^ sw)) = 0;
            *(short*)(rb + (204 ^ sw)) = 0;
            *(short*)(rb + (206 ^ sw)) = 0;
            *(uint4*)(rb + (208 ^ sw)) = (uint4){0, 0, 0, 0};
        }
    }
    __syncthreads();

    // C: 3x layer32 + fused layer-4/reduction
    layer32<7,  8, 2, true >(buf, wfWi,  biases,        lane, w * 2);
    __syncthreads();
    layer32<16, 8, 2, true >(buf, wfWh1, biases + 256,  lane, w * 2);
    __syncthreads();
    layer32<16, 8, 2, true >(buf, wfWh2, biases + 512,  lane, w * 2);
    __syncthreads();
    layer4_reduce(buf, wfWo, biases + 768, noise, s_l32, Wz2, Wzw, lane, w);
    __syncthreads();

    // Final combine: per-pair incr = -||z||^2*dt + 0.5*(z.(w-sdt) + z_new.(w+sdt));
    // wave-reduce the block's 32 pair values and atomically add to yout[b].
    if (tid < 32) {
        const int rr = tid * 2;
        float sz2 = 0.f, szw0 = 0.f, szw1 = 0.f;
#pragma unroll
        for (int ww = 0; ww < 4; ++ww) {
            sz2  += Wz2[ww * 64 + rr];
            szw0 += Wzw[ww * 64 + rr];
            szw1 += Wzw[ww * 64 + rr + 1];
        }
        float v = -sz2 * DT_ + 0.5f * (szw0 + szw1);
        v += __shfl_xor(v, 1);  v += __shfl_xor(v, 2);
        v += __shfl_xor(v, 4);  v += __shfl_xor(v, 8);
        v += __shfl_xor(v, 16);
        if (tid == 0) atomicAdd(&yout[b], v);
    }
}

// ---------------------------------------------------------------------------
extern "C" void kernel_launch(void* const* d_in, const int* in_sizes, int n_in,
                              void* d_out, int out_size, void* d_ws, size_t ws_size,
                              hipStream_t stream) {
    (void)in_sizes; (void)n_in; (void)out_size; (void)ws_size;
    const float* Wn    = (const float*)d_in[0];
    const int*   signs = (const int*)d_in[1];
    const float* x0    = (const float*)d_in[2];
    const float* y0    = (const float*)d_in[3];
    const float* Wi    = (const float*)d_in[4];
    const float* bi    = (const float*)d_in[5];
    const float* Wh1   = (const float*)d_in[6];
    const float* bh1   = (const float*)d_in[7];
    const float* Wh2   = (const float*)d_in[8];
    const float* bh2   = (const float*)d_in[9];
    const float* Wo    = (const float*)d_in[10];
    const float* bo    = (const float*)d_in[11];

    float* out  = (float*)d_out;
    float* xout = out;                       // [2048,100]
    float* yout = out + (size_t)B_SZ * DX;   // [2048,1]

    char* ws = (char*)d_ws;
    size_t off = 0;
    bf16*  wfWi   = (bf16*)(ws + off); off += 28672 * sizeof(bf16);   // KC=7,  8 tiles
    bf16*  wfWh1  = (bf16*)(ws + off); off += 65536 * sizeof(bf16);   // KC=16, 8 tiles
    bf16*  wfWh2  = (bf16*)(ws + off); off += 65536 * sizeof(bf16);
    bf16*  wfWo   = (bf16*)(ws + off); off += 32768 * sizeof(bf16);   // KC=16, 4 tiles
    float* biases = (float*)(ws + off); off += 896 * sizeof(float);
    float* xckpt  = (float*)(ws + off); off += (size_t)B_SZ * 4 * DX * sizeof(float);  // 3.3MB

    prep_kernel<<<756 + B_SZ, 256, 0, stream>>>(
        Wn, x0, y0, Wi, Wh1, Wh2, Wo, bi, bh1, bh2, bo,
        wfWi, wfWh1, wfWh2, wfWo, biases, xckpt, xout, yout);
    mlp_kernel<<<B_SZ * 4, 256, 0, stream>>>(Wn, signs, xckpt,
                                             wfWi, wfWh1, wfWh2, wfWo, biases, yout);
}